// Round 1
// baseline (358.655 us; speedup 1.0000x reference)
//
#include <hip/hip_runtime.h>
#include <hip/hip_bf16.h>
#include <stdint.h>

typedef __bf16 bf16_t;
typedef __bf16 bf16x8 __attribute__((ext_vector_type(8)));
typedef __bf16 bf16x4 __attribute__((ext_vector_type(4)));
typedef float f32x4 __attribute__((ext_vector_type(4)));

#define AS1 __attribute__((address_space(1)))
#define AS3 __attribute__((address_space(3)))

static __device__ __forceinline__ void gload_lds16(const void* g, void* l) {
  __builtin_amdgcn_global_load_lds((const AS1 void*)g, (AS3 void*)l, 16, 0, 0);
}

// ---------------- fp32 -> bf16 convert (vectorized x4) ----------------
__global__ void cvt_f32_bf16(const float* __restrict__ in, bf16_t* __restrict__ out, int n4) {
  int i = blockIdx.x * blockDim.x + threadIdx.x;
  if (i >= n4) return;
  float4 v = ((const float4*)in)[i];
  bf16x4 o;
  o[0] = (bf16_t)v.x; o[1] = (bf16_t)v.y; o[2] = (bf16_t)v.z; o[3] = (bf16_t)v.w;
  *(bf16x4*)(out + (size_t)i * 4) = o;
}

// ---------------- GEMM C = A(MxK) * B(NxK)^T, bf16 in, fp32 acc ----------------
// MODE 0: qkv epilogue (+bias, q*=0.125, scatter to (B,nh,T,hs) bf16)
// MODE 1: proj epilogue (+bias, fp32 row-major out)
template<int MODE>
__global__ __launch_bounds__(256) void gemm_bt(
    const bf16_t* __restrict__ A, const bf16_t* __restrict__ Bw,
    const float* __restrict__ bias, void* __restrict__ Cout,
    int M, int N, int K)
{
  __shared__ bf16_t As[128 * 32];
  __shared__ bf16_t Bs[128 * 32];
  const int tid = threadIdx.x;
  const int wave = tid >> 6, lane = tid & 63;
  const int l15 = lane & 15, l4 = lane >> 4;
  const int m0 = blockIdx.y * 128, n0 = blockIdx.x * 128;
  const int wm = (wave >> 1) * 64, wn = (wave & 1) * 64;
  f32x4 acc[4][4] = {};

  const int r = tid >> 2;
  const int cb = (tid & 3) * 16;  // byte offset within 64B row-chunk
  const char* gA0 = (const char*)(A + (size_t)(m0 + r) * K) + cb;
  const char* gA1 = (const char*)(A + (size_t)(m0 + 64 + r) * K) + cb;
  const char* gB0 = (const char*)(Bw + (size_t)(n0 + r) * K) + cb;
  const char* gB1 = (const char*)(Bw + (size_t)(n0 + 64 + r) * K) + cb;
  char* lA = (char*)As + tid * 16;
  char* lB = (char*)Bs + tid * 16;

  for (int k0 = 0; k0 < K; k0 += 32) {
    const size_t koff = (size_t)k0 * 2;
    gload_lds16(gA0 + koff, lA);
    gload_lds16(gA1 + koff, lA + 4096);
    gload_lds16(gB0 + koff, lB);
    gload_lds16(gB1 + koff, lB + 4096);
    __syncthreads();
    bf16x8 af[4], bfr[4];
#pragma unroll
    for (int mt = 0; mt < 4; ++mt)
      af[mt] = *(const bf16x8*)&As[(wm + mt * 16 + l15) * 32 + l4 * 8];
#pragma unroll
    for (int nt = 0; nt < 4; ++nt)
      bfr[nt] = *(const bf16x8*)&Bs[(wn + nt * 16 + l15) * 32 + l4 * 8];
#pragma unroll
    for (int mt = 0; mt < 4; ++mt)
#pragma unroll
      for (int nt = 0; nt < 4; ++nt)
        acc[mt][nt] = __builtin_amdgcn_mfma_f32_16x16x32_bf16(af[mt], bfr[nt], acc[mt][nt], 0, 0, 0);
    __syncthreads();
  }

  if (MODE == 0) {
    bf16_t* qkv = (bf16_t*)Cout;
#pragma unroll
    for (int mt = 0; mt < 4; ++mt) {
#pragma unroll
      for (int nt = 0; nt < 4; ++nt) {
        const int col = n0 + wn + nt * 16 + l15;
        const float bv = bias[col];
        const int which = col >> 10;       // 0=q 1=k 2=v
        const int c = col & 1023;
        const int head = c >> 6, d = c & 63;
#pragma unroll
        for (int i = 0; i < 4; ++i) {
          const int row = m0 + wm + mt * 16 + l4 * 4 + i;
          const int bb = row >> 11, t = row & 2047;
          float v = acc[mt][nt][i] + bv;
          if (which == 0) v *= 0.125f;  // fold 1/sqrt(hs); exact power of 2
          qkv[(size_t)which * 8388608 + ((size_t)((bb * 16 + head) * 2048 + t) << 6) + d] = (bf16_t)v;
        }
      }
    }
  } else {
    float* C = (float*)Cout;
#pragma unroll
    for (int mt = 0; mt < 4; ++mt) {
#pragma unroll
      for (int nt = 0; nt < 4; ++nt) {
        const int col = n0 + wn + nt * 16 + l15;
        const float bv = bias[col];
#pragma unroll
        for (int i = 0; i < 4; ++i) {
          const int row = m0 + wm + mt * 16 + l4 * 4 + i;
          C[(size_t)row * N + col] = acc[mt][nt][i] + bv;
        }
      }
    }
  }
}

// ---------------- causal flash attention ----------------
// Q,K,V: (B*nh, T, hs) bf16, Q pre-scaled by 1/8. Y: (B, T, C) bf16.
// grid: (T/64, B*nh), block 256. 4 waves x 16 q-rows, KVBLK=64.
__global__ __launch_bounds__(256) void flash_attn(
    const bf16_t* __restrict__ Qg, const bf16_t* __restrict__ Kg,
    const bf16_t* __restrict__ Vg, bf16_t* __restrict__ Y)
{
  const int T = 2048, HS = 64;
  const int qt = blockIdx.x, bh = blockIdx.y;
  const int q0 = qt * 64;
  const size_t base = (size_t)bh * T * HS;

  __shared__ bf16_t Kt[64 * 72];  // padded: 72 elems/row -> 2-way max conflicts
  __shared__ bf16_t VT[64 * 72];  // transposed V: VT[d][k]
  __shared__ bf16_t Ps[64 * 72];  // P tile (per-wave private rows)

  const int tid = threadIdx.x;
  const int wave = tid >> 6, lane = tid & 63;
  const int l15 = lane & 15, l4 = lane >> 4;

  // Q fragments for this wave's 16 rows, hoisted to registers
  bf16x8 aq[2];
  {
    const bf16_t* qrow = Qg + base + (size_t)(q0 + wave * 16 + l15) * HS;
    aq[0] = *(const bf16x8*)(qrow + l4 * 8);
    aq[1] = *(const bf16x8*)(qrow + 32 + l4 * 8);
  }

  float m_i[4], l_i[4];
  f32x4 oacc[4] = {};
#pragma unroll
  for (int i = 0; i < 4; ++i) { m_i[i] = -1e30f; l_i[i] = 0.f; }

  for (int kt = 0; kt <= qt; ++kt) {
    const int k0 = kt * 64;
    __syncthreads();  // prior tile's reads complete before restage
    {
      // stage K tile [64][64] -> Kt (padded 72)
      const int kr = tid >> 2;
      const int c16 = (tid & 3) * 16;
      const bf16_t* src = Kg + base + (size_t)(k0 + kr) * HS + c16;
      *(bf16x8*)&Kt[kr * 72 + c16] = *(const bf16x8*)src;
      *(bf16x8*)&Kt[kr * 72 + c16 + 8] = *(const bf16x8*)(src + 8);
      // stage V tile transposed -> VT[d][k]
      const int vk = tid & 63;
      const int d0 = (tid >> 6) * 16;
      const bf16_t* vrow = Vg + base + (size_t)(k0 + vk) * HS + d0;
      bf16x8 v0 = *(const bf16x8*)vrow;
      bf16x8 v1 = *(const bf16x8*)(vrow + 8);
#pragma unroll
      for (int j = 0; j < 8; ++j) {
        VT[(d0 + j) * 72 + vk] = v0[j];
        VT[(d0 + 8 + j) * 72 + vk] = v1[j];
      }
    }
    __syncthreads();

    // S = Q K^T (16 q-rows x 64 k-cols per wave)
    f32x4 s[4];
#pragma unroll
    for (int nt = 0; nt < 4; ++nt) {
      bf16x8 b0 = *(const bf16x8*)&Kt[(nt * 16 + l15) * 72 + l4 * 8];
      bf16x8 b1 = *(const bf16x8*)&Kt[(nt * 16 + l15) * 72 + 32 + l4 * 8];
      f32x4 t = {};
      t = __builtin_amdgcn_mfma_f32_16x16x32_bf16(aq[0], b0, t, 0, 0, 0);
      t = __builtin_amdgcn_mfma_f32_16x16x32_bf16(aq[1], b1, t, 0, 0, 0);
      s[nt] = t;
    }
    if (kt == qt) {  // diagonal tile: mask k > q (local indices comparable: q0==k0)
#pragma unroll
      for (int nt = 0; nt < 4; ++nt)
#pragma unroll
        for (int i = 0; i < 4; ++i) {
          const int q = wave * 16 + l4 * 4 + i;
          const int k = nt * 16 + l15;
          if (k > q) s[nt][i] = -1e30f;
        }
    }

    // online softmax (rows spread over 16-lane group, 4 rows/lane)
    float pm[4];
#pragma unroll
    for (int i = 0; i < 4; ++i)
      pm[i] = fmaxf(fmaxf(s[0][i], s[1][i]), fmaxf(s[2][i], s[3][i]));
#pragma unroll
    for (int i = 0; i < 4; ++i) {
      pm[i] = fmaxf(pm[i], __shfl_xor(pm[i], 1));
      pm[i] = fmaxf(pm[i], __shfl_xor(pm[i], 2));
      pm[i] = fmaxf(pm[i], __shfl_xor(pm[i], 4));
      pm[i] = fmaxf(pm[i], __shfl_xor(pm[i], 8));
    }
    float sc[4];
#pragma unroll
    for (int i = 0; i < 4; ++i) {
      const float mnew = fmaxf(m_i[i], pm[i]);
      sc[i] = __expf(m_i[i] - mnew);
      m_i[i] = mnew;
    }
    float rsum[4] = {0.f, 0.f, 0.f, 0.f};
#pragma unroll
    for (int nt = 0; nt < 4; ++nt)
#pragma unroll
      for (int i = 0; i < 4; ++i) {
        const float p = __expf(s[nt][i] - m_i[i]);
        s[nt][i] = p;
        rsum[i] += p;
      }
#pragma unroll
    for (int i = 0; i < 4; ++i) {
      rsum[i] += __shfl_xor(rsum[i], 1);
      rsum[i] += __shfl_xor(rsum[i], 2);
      rsum[i] += __shfl_xor(rsum[i], 4);
      rsum[i] += __shfl_xor(rsum[i], 8);
      l_i[i] = l_i[i] * sc[i] + rsum[i];
    }
#pragma unroll
    for (int dt = 0; dt < 4; ++dt)
#pragma unroll
      for (int i = 0; i < 4; ++i) oacc[dt][i] *= sc[i];

    // P -> LDS (wave-private rows), then PV
#pragma unroll
    for (int nt = 0; nt < 4; ++nt)
#pragma unroll
      for (int i = 0; i < 4; ++i)
        Ps[(wave * 16 + l4 * 4 + i) * 72 + nt * 16 + l15] = (bf16_t)s[nt][i];

    bf16x8 pa[2];
    pa[0] = *(const bf16x8*)&Ps[(wave * 16 + l15) * 72 + l4 * 8];
    pa[1] = *(const bf16x8*)&Ps[(wave * 16 + l15) * 72 + 32 + l4 * 8];
#pragma unroll
    for (int dt = 0; dt < 4; ++dt) {
      bf16x8 vb0 = *(const bf16x8*)&VT[(dt * 16 + l15) * 72 + l4 * 8];
      bf16x8 vb1 = *(const bf16x8*)&VT[(dt * 16 + l15) * 72 + 32 + l4 * 8];
      oacc[dt] = __builtin_amdgcn_mfma_f32_16x16x32_bf16(pa[0], vb0, oacc[dt], 0, 0, 0);
      oacc[dt] = __builtin_amdgcn_mfma_f32_16x16x32_bf16(pa[1], vb1, oacc[dt], 0, 0, 0);
    }
  }

  // epilogue: O / l, write (B,T,C) bf16
  const int b = bh >> 4, h = bh & 15;
#pragma unroll
  for (int dt = 0; dt < 4; ++dt)
#pragma unroll
    for (int i = 0; i < 4; ++i) {
      const int q = q0 + wave * 16 + l4 * 4 + i;
      const int d = dt * 16 + l15;
      const float v = oacc[dt][i] / l_i[i];
      Y[((size_t)(b * T + q)) * 1024 + h * 64 + d] = (bf16_t)v;
    }
}

// ---------------- launch ----------------
extern "C" void kernel_launch(void* const* d_in, const int* in_sizes, int n_in,
                              void* d_out, int out_size, void* d_ws, size_t ws_size,
                              hipStream_t stream) {
  const float* x      = (const float*)d_in[0];  // (4,2048,1024)
  const float* w_attn = (const float*)d_in[1];  // (3072,1024)
  const float* b_attn = (const float*)d_in[2];  // (3072,)
  const float* w_proj = (const float*)d_in[3];  // (1024,1024)
  const float* b_proj = (const float*)d_in[4];  // (1024,)
  float* out = (float*)d_out;

  char* ws = (char*)d_ws;
  bf16_t* xb   = (bf16_t*)(ws);                       // 16 MB
  bf16_t* wab  = (bf16_t*)(ws + 16777216);            // 6 MB
  bf16_t* wpb  = (bf16_t*)(ws + 23068672);            // 2 MB
  bf16_t* qkvb = (bf16_t*)(ws + 25165824);            // 48 MB (q,k,v each 16MB)
  bf16_t* yb   = (bf16_t*)(ws + 75497472);            // 16 MB   (total 88 MB)

  cvt_f32_bf16<<<8192, 256, 0, stream>>>(x, xb, 2097152);
  cvt_f32_bf16<<<3072, 256, 0, stream>>>(w_attn, wab, 786432);
  cvt_f32_bf16<<<1024, 256, 0, stream>>>(w_proj, wpb, 262144);

  dim3 g1(24, 64);  // N/128, M/128
  gemm_bt<0><<<g1, 256, 0, stream>>>(xb, wab, b_attn, (void*)qkvb, 8192, 3072, 1024);

  dim3 g2(32, 64);  // qtiles, B*nh
  flash_attn<<<g2, 256, 0, stream>>>(qkvb, qkvb + 8388608, qkvb + 16777216, yb);

  dim3 g3(8, 64);
  gemm_bt<1><<<g3, 256, 0, stream>>>(yb, wpb, b_proj, (void*)out, 8192, 1024, 1024);
}